// Round 1
// 384.899 us; speedup vs baseline: 1.0489x; 1.0489x over previous
//
#include <hip/hip_runtime.h>
#include <stdint.h>

#define NSCENE 16
#define NPED 32
#define HD 64
#define ED 64
#define D1 8192
#define BOTN 1024

typedef unsigned short ushort_t;
typedef __attribute__((ext_vector_type(4))) float f32x4;
typedef __attribute__((ext_vector_type(8))) __bf16 bf16x8;  // gfx950 mfma operand
typedef __attribute__((ext_vector_type(4))) unsigned int u32x4;
typedef __attribute__((ext_vector_type(2))) unsigned int u32x2;

__device__ __forceinline__ float bf2f(ushort_t u) {
  union { unsigned int i; float f; } x;
  x.i = ((unsigned int)u) << 16;
  return x.f;
}

__device__ __forceinline__ ushort_t f2bf(float f) {
  union { float f; unsigned int i; } x;
  x.f = f;
  unsigned int u = x.i + 0x7fffu + ((x.i >> 16) & 1u);
  return (ushort_t)(u >> 16);
}

// pack two f32 -> two bf16 RNE (lo in bits [15:0])
__device__ __forceinline__ unsigned int packbf(float lo, float hi) {
#if __has_builtin(__builtin_amdgcn_cvt_pk_bf16_f32)
  typedef __attribute__((ext_vector_type(2))) __bf16 bf16x2_t;
  union { bf16x2_t v; unsigned int u; } x;
  x.v = __builtin_amdgcn_cvt_pk_bf16_f32(lo, hi);
  return x.u;
#else
  return (unsigned int)f2bf(lo) | ((unsigned int)f2bf(hi) << 16);
#endif
}

// unpack u32 holding 2 bf16 -> 2 f32
__device__ __forceinline__ void unpk(unsigned int u, float& lo, float& hi) {
  union { unsigned int i; float f; } a, b;
  a.i = u << 16;
  b.i = u & 0xffff0000u;
  lo = a.f;
  hi = b.f;
}

__device__ __forceinline__ float clip1(float x) {
  return fminf(fmaxf(x, -1.f), 1.f);
}

// async global->LDS DMA, 16B/lane; casts through integers (legal reinterpret).
// HW: LDS dest = wave-uniform base + lane*16 — caller arranges that.
__device__ __forceinline__ void async_load16(const void* g, void* l) {
  __builtin_amdgcn_global_load_lds(
      (const __attribute__((address_space(1))) unsigned int*)(unsigned long long)g,
      (__attribute__((address_space(3))) unsigned int*)(unsigned int)(unsigned long long)l,
      16, 0, 0);
}

// ---------------------------------------------------------------------------
// k_pre: ALL preprocessing in one kernel of independent blocks. (unchanged)
// ---------------------------------------------------------------------------
__global__ __launch_bounds__(256) void k_pre(
    const void* __restrict__ hv_, const void* __restrict__ end_posv,
    const void* __restrict__ W_spv, const void* __restrict__ b_spv,
    const void* __restrict__ W1v, const void* __restrict__ b1v,
    const void* __restrict__ W2v, const void* __restrict__ b2v,
    int* __restrict__ flag, float* __restrict__ epf, float* __restrict__ b2f,
    float* __restrict__ M0, float* __restrict__ M1,
    ushort_t* __restrict__ hcb, ushort_t* __restrict__ W2T) {
  __shared__ ushort_t tile[64][72];
  __shared__ int cnt[256];
  __shared__ int isbf_sh;
  const int t = threadIdx.x;
  const int bid = blockIdx.x;

  // ---- inline dtype detection ----
  {
    const ushort_t* wu = (const ushort_t*)W1v;
    unsigned int u = wu[2 * t];
    int e = (u >> 7) & 0xff;
    cnt[t] = (e >= 90 && e <= 140) ? 1 : 0;
    __syncthreads();
    for (int ofs = 128; ofs > 0; ofs >>= 1) {
      if (t < ofs) cnt[t] += cnt[t + ofs];
      __syncthreads();
    }
    if (t == 0) isbf_sh = (cnt[0] >= 128) ? 1 : 0;
    __syncthreads();
  }
  const int isbf = isbf_sh;

  if (bid < 256) {
    // ================= hc: hcb[j][k] = hbias[k] + h[j]@W1[64:] =============
    const int kb = bid & 7, jt = bid >> 3;
    const int kbase = kb * 1024 + t * 4;
    float hb0, hb1, hb2, hb3;
    if (isbf) {
      const ushort_t* b1u = (const ushort_t*)b1v;
      const ushort_t* bspu = (const ushort_t*)b_spv;
      const ushort_t* wp = (const ushort_t*)W1v + kbase;
      hb0 = bf2f(b1u[kbase]); hb1 = bf2f(b1u[kbase + 1]);
      hb2 = bf2f(b1u[kbase + 2]); hb3 = bf2f(b1u[kbase + 3]);
      for (int e = 0; e < ED; ++e) {
        float bs = bf2f(bspu[e]);
        u32x2 wv = *(const u32x2*)(wp + (size_t)e * D1);
        float w0, w1, w2, w3;
        unpk(wv.x, w0, w1); unpk(wv.y, w2, w3);
        hb0 += bs * w0; hb1 += bs * w1; hb2 += bs * w2; hb3 += bs * w3;
      }
    } else {
      const float* b1f = (const float*)b1v;
      const float* bspf = (const float*)b_spv;
      const float* wp = (const float*)W1v + kbase;
      hb0 = b1f[kbase]; hb1 = b1f[kbase + 1];
      hb2 = b1f[kbase + 2]; hb3 = b1f[kbase + 3];
      for (int e = 0; e < ED; ++e) {
        float bs = bspf[e];
        float4 w = *(const float4*)(wp + (size_t)e * D1);
        hb0 += bs * w.x; hb1 += bs * w.y; hb2 += bs * w.z; hb3 += bs * w.w;
      }
    }
    float acc[16][4];
#pragma unroll
    for (int j = 0; j < 16; ++j)
#pragma unroll
      for (int c = 0; c < 4; ++c) acc[j][c] = 0.f;
    if (isbf) {
      const ushort_t* wp = (const ushort_t*)W1v + (size_t)ED * D1 + kbase;
      const ushort_t* hp = (const ushort_t*)hv_ + jt * 16 * HD;
      for (int hh = 0; hh < HD; ++hh) {
        u32x2 wv = *(const u32x2*)(wp + (size_t)hh * D1);
        float w0, w1, w2, w3;
        unpk(wv.x, w0, w1); unpk(wv.y, w2, w3);
#pragma unroll
        for (int j = 0; j < 16; ++j) {
          float hj = bf2f(hp[j * HD + hh]);
          acc[j][0] += hj * w0;
          acc[j][1] += hj * w1;
          acc[j][2] += hj * w2;
          acc[j][3] += hj * w3;
        }
      }
    } else {
      const float* wp = (const float*)W1v + (size_t)ED * D1 + kbase;
      const float* hp = (const float*)hv_ + jt * 16 * HD;
#pragma unroll 4
      for (int hh = 0; hh < HD; ++hh) {
        float4 w = *(const float4*)(wp + (size_t)hh * D1);
#pragma unroll
        for (int j = 0; j < 16; ++j) {
          float hj = hp[j * HD + hh];
          acc[j][0] += hj * w.x;
          acc[j][1] += hj * w.y;
          acc[j][2] += hj * w.z;
          acc[j][3] += hj * w.w;
        }
      }
    }
#pragma unroll
    for (int j = 0; j < 16; ++j) {
      u32x2 pk;
      pk.x = packbf(acc[j][0] + hb0, acc[j][1] + hb1);
      pk.y = packbf(acc[j][2] + hb2, acc[j][3] + hb3);
      *(u32x2*)(hcb + (size_t)(jt * 16 + j) * D1 + kbase) = pk;
    }
  } else if (bid < 2304) {
    // ================= W2 transpose =================
    const int idx = bid - 256;
    const int kt = idx & 127, nt = idx >> 7;
    const int r = t >> 3, c8 = (t & 7) * 8;
#pragma unroll
    for (int i = 0; i < 2; ++i) {
      int row = i * 32 + r;
      size_t base = (size_t)(kt * 64 + row) * BOTN + nt * 64 + c8;
      if (isbf) {
        u32x4 v = *(const u32x4*)((const ushort_t*)W2v + base);
        *(u32x4*)&tile[row][c8] = v;
      } else {
        const float* src = (const float*)W2v + base;
        float4 w0 = *(const float4*)src;
        float4 w1 = *(const float4*)(src + 4);
        u32x4 pk;
        pk.x = packbf(w0.x, w0.y);
        pk.y = packbf(w0.z, w0.w);
        pk.z = packbf(w1.x, w1.y);
        pk.w = packbf(w1.z, w1.w);
        *(u32x4*)&tile[row][c8] = pk;
      }
    }
    __syncthreads();
#pragma unroll
    for (int i = 0; i < 2; ++i) {
      int nrow = i * 32 + r;
      union { ushort_t us[8]; u32x4 v; } pk;
#pragma unroll
      for (int jj = 0; jj < 8; ++jj) pk.us[jj] = tile[c8 + jj][nrow];
      *(u32x4*)(W2T + (size_t)(nt * 64 + nrow) * D1 + kt * 64 + c8) = pk.v;
    }
  } else if (bid < 2336) {
    // ================= M0/M1 fold =================
    const int k = (bid - 2304) * 256 + t;
    float m0 = 0.f, m1 = 0.f;
    if (isbf) {
      const ushort_t* Wspu = (const ushort_t*)W_spv;
      const ushort_t* W1u = (const ushort_t*)W1v;
      for (int e = 0; e < ED; ++e) {
        float w = bf2f(W1u[e * D1 + k]);
        m0 += bf2f(Wspu[e]) * w;
        m1 += bf2f(Wspu[ED + e]) * w;
      }
    } else {
      const float* Wspf = (const float*)W_spv;
      const float* W1f = (const float*)W1v;
      for (int e = 0; e < ED; ++e) {
        float w = W1f[e * D1 + k];
        m0 += Wspf[e] * w;
        m1 += Wspf[ED + e] * w;
      }
    }
    M0[k] = m0;
    M1[k] = m1;
  } else {
    // ================= epf / b2f / flag =================
    if (t == 0) *flag = isbf;
    const ushort_t* epu = (const ushort_t*)end_posv;
    const float* epff = (const float*)end_posv;
    const ushort_t* b2u = (const ushort_t*)b2v;
    const float* b2ff = (const float*)b2v;
    for (int i = t; i < 1024; i += 256) {
      epf[i] = isbf ? bf2f(epu[i]) : epff[i];
      b2f[i] = isbf ? bf2f(b2u[i]) : b2ff[i];
    }
  }
}

// ---------------------------------------------------------------------------
// k_gemm v2: BM=256 BN=256 BK=64, 512 thr (8 waves, 4m x 2n, wave = 64m x 128n).
// Grid 256 = exactly 1 block/CU, single pass, no tail.
// Double-buffered A *and* B; one raw barrier per K-step with vmcnt(0) drain
// at the END (T3/T4 minimal pattern): DMA of tile t+1 + A-gen(t+1) hide under
// MFMA(t). Both LDS operands use the XOR chunk swizzle (slot = chunk^(row&7))
// -> bank-balanced ds_read_b128 / ds_write_b128, no padding (DMA-compatible).
// XCD-aware decode: bid%8 = XCD; two XCDs share one 4 MB W2T quarter -> L2.
// ---------------------------------------------------------------------------
#define BM 256
#define BN 256

__global__ __launch_bounds__(512, 2) void k_gemm(
    const ushort_t* __restrict__ hcb, const float* __restrict__ M0f,
    const float* __restrict__ M1f, const ushort_t* __restrict__ W2T,
    const float* __restrict__ epf, const float* __restrict__ b2f,
    const int* __restrict__ flag, void* __restrict__ outv) {
  __shared__ ushort_t aLds[2][BM * 64];  // 2 x 32 KB, swizzled chunks
  __shared__ ushort_t bLds[2][BN * 64];  // 2 x 32 KB, swizzled chunks
  __shared__ float2 rrLds[BM];

  const int t = threadIdx.x;
  const int w = t >> 6;
  const int lane = t & 63;

  // XCD-aware decode (grid 256 = 8 XCDs x 32 blocks)
  const int xcd = blockIdx.x & 7;
  const int idx = blockIdx.x >> 3;
  const int nb = xcd >> 1;                // N quarter (256 cols); 2 XCDs/quarter
  const int mb = ((xcd & 1) << 5) | idx;  // 0..63 M tile (256 rows)
  const int s = mb >> 2;                  // scene
  const int a0 = (mb & 3) << 3;           // first of 8 a-values
  const int isbf = *flag;

  if (t < BM) {
    int al = t >> 5, b = t & 31;
    int pa = s * NPED + a0 + al, pb = s * NPED + b;
    float r0 = epf[pb * 2] - epf[pa * 2];
    float r1 = epf[pb * 2 + 1] - epf[pa * 2 + 1];
    rrLds[t] = make_float2(clip1(r0), clip1(r1));
  }
  __syncthreads();

  // ---- A-gen: thread owns rows {g*64+bq, g=0..3} (same b, same hv!), chunk kc
  const int bq = t >> 3;  // 0..63
  const int kc = t & 7;   // 0..7
  float rr0[4], rr1[4];
#pragma unroll
  for (int g = 0; g < 4; ++g) {
    float2 v = rrLds[g * 64 + bq];
    rr0[g] = v.x;
    rr1[g] = v.y;
  }
  const ushort_t* hcRow = hcb + (size_t)(s * NPED + (bq & 31)) * D1 + kc * 8;
  const float* m0p = M0f + kc * 8;
  const float* m1p = M1f + kc * 8;
  ushort_t* aW0 = &aLds[0][bq * 64 + (kc ^ (bq & 7)) * 8];
  ushort_t* aW1 = &aLds[1][bq * 64 + (kc ^ (bq & 7)) * 8];

  // ---- B DMA: lane covers row (i*64 + w*8 + (lane>>3)), LDS slot lane&7.
  // LDS dest byte = i*8192 + w*1024 + lane*16  (wave-uniform + lane*16). ----
  const int rowl = w * 8 + (lane >> 3);
  const int chl = (lane & 7) ^ (lane >> 3);  // fetch chunk = slot ^ (row&7)
  const ushort_t* bGlob = W2T + (size_t)(nb * BN + rowl) * D1 + chl * 8;
  ushort_t* bW0 = &bLds[0][rowl * 64 + (lane & 7) * 8];
  ushort_t* bW1 = &bLds[1][rowl * 64 + (lane & 7) * 8];

  // ---- MFMA fragment addressing ----
  const int wm = w >> 1, wn = w & 1;
  const int rl = lane & 15, q = lane >> 4, r7 = rl & 7;
  const int aR0 = (wm * 64 + rl) * 64 + (q ^ r7) * 8;        // ki=0 (+mt*1024)
  const int aR1 = (wm * 64 + rl) * 64 + ((q + 4) ^ r7) * 8;  // ki=1
  const int bR0 = (wn * 128 + rl) * 64 + (q ^ r7) * 8;       // (+nt*1024)
  const int bR1 = (wn * 128 + rl) * 64 + ((q + 4) ^ r7) * 8;

  f32x4 acc[4][8];
#pragma unroll
  for (int mt = 0; mt < 4; ++mt)
#pragma unroll
    for (int nt = 0; nt < 8; ++nt) acc[mt][nt] = (f32x4){0.f, 0.f, 0.f, 0.f};

  // ================= prologue: stage + A-gen tile 0 =================
#pragma unroll
  for (int i = 0; i < 4; ++i)
    async_load16(bGlob + (size_t)i * 64 * D1, bW0 + i * 64 * 64);
  {
    u32x4 hv = *(const u32x4*)(hcRow);
    float4 A0 = *(const float4*)(m0p);
    float4 A1 = *(const float4*)(m0p + 4);
    float4 C0 = *(const float4*)(m1p);
    float4 C1 = *(const float4*)(m1p + 4);
    float h0, h1, h2, h3, h4, h5, h6, h7;
    unpk(hv.x, h0, h1); unpk(hv.y, h2, h3);
    unpk(hv.z, h4, h5); unpk(hv.w, h6, h7);
#pragma unroll
    for (int g = 0; g < 4; ++g) {
      float r0 = rr0[g], r1 = rr1[g];
      u32x4 pk;
      pk.x = packbf(fmaxf(h0 + r0 * A0.x + r1 * C0.x, 0.f),
                    fmaxf(h1 + r0 * A0.y + r1 * C0.y, 0.f));
      pk.y = packbf(fmaxf(h2 + r0 * A0.z + r1 * C0.z, 0.f),
                    fmaxf(h3 + r0 * A0.w + r1 * C0.w, 0.f));
      pk.z = packbf(fmaxf(h4 + r0 * A1.x + r1 * C1.x, 0.f),
                    fmaxf(h5 + r0 * A1.y + r1 * C1.y, 0.f));
      pk.w = packbf(fmaxf(h6 + r0 * A1.z + r1 * C1.z, 0.f),
                    fmaxf(h7 + r0 * A1.w + r1 * C1.w, 0.f));
      *(u32x4*)(aW0 + g * 64 * 64) = pk;
    }
  }
  __syncthreads();  // full drain OK once, in prologue

  // ================= main loop: 127 pipelined K-steps =================
  int cur = 0;
  for (int kt = 0; kt < D1 / 64 - 1; ++kt) {
    const int k0n = (kt + 1) * 64;
    // --- issue next B tile DMA (in flight across the MFMA phase) ---
    {
      const ushort_t* src = bGlob + k0n;
      ushort_t* dst = cur ? bW0 : bW1;
#pragma unroll
      for (int i = 0; i < 4; ++i)
        async_load16(src + (size_t)i * 64 * D1, dst + i * 64 * 64);
    }
    // --- issue next A-gen operand loads early (consumed after MFMA) ---
    u32x4 hv = *(const u32x4*)(hcRow + k0n);
    float4 A0 = *(const float4*)(m0p + k0n);
    float4 A1 = *(const float4*)(m0p + k0n + 4);
    float4 C0 = *(const float4*)(m1p + k0n);
    float4 C1 = *(const float4*)(m1p + k0n + 4);

    // --- MFMA phase on current buffers ---
    {
      const ushort_t* ab = cur ? &aLds[1][0] : &aLds[0][0];
      const ushort_t* bb = cur ? &bLds[1][0] : &bLds[0][0];
#pragma unroll
      for (int ki = 0; ki < 2; ++ki) {
        const int ao = ki ? aR1 : aR0;
        const int bo = ki ? bR1 : bR0;
        bf16x8 af[4];
#pragma unroll
        for (int mt = 0; mt < 4; ++mt)
          af[mt] = *(const bf16x8*)(ab + ao + mt * 1024);
#pragma unroll
        for (int nh = 0; nh < 2; ++nh) {
          bf16x8 bfr[4];
#pragma unroll
          for (int j = 0; j < 4; ++j)
            bfr[j] = *(const bf16x8*)(bb + bo + (nh * 4 + j) * 1024);
#pragma unroll
          for (int mt = 0; mt < 4; ++mt)
#pragma unroll
            for (int j = 0; j < 4; ++j)
              acc[mt][nh * 4 + j] = __builtin_amdgcn_mfma_f32_16x16x32_bf16(
                  af[mt], bfr[j], acc[mt][nh * 4 + j], 0, 0, 0);
        }
      }
    }

    // --- A-gen(kt+1): VALU + ds_write into the OTHER A buffer ---
    {
      float h0, h1, h2, h3, h4, h5, h6, h7;
      unpk(hv.x, h0, h1); unpk(hv.y, h2, h3);
      unpk(hv.z, h4, h5); unpk(hv.w, h6, h7);
      ushort_t* aw = cur ? aW0 : aW1;
#pragma unroll
      for (int g = 0; g < 4; ++g) {
        float r0 = rr0[g], r1 = rr1[g];
        u32x4 pk;
        pk.x = packbf(fmaxf(h0 + r0 * A0.x + r1 * C0.x, 0.f),
                      fmaxf(h1 + r0 * A0.y + r1 * C0.y, 0.f));
        pk.y = packbf(fmaxf(h2 + r0 * A0.z + r1 * C0.z, 0.f),
                      fmaxf(h3 + r0 * A0.w + r1 * C0.w, 0.f));
        pk.z = packbf(fmaxf(h4 + r0 * A1.x + r1 * C1.x, 0.f),
                      fmaxf(h5 + r0 * A1.y + r1 * C1.y, 0.f));
        pk.w = packbf(fmaxf(h6 + r0 * A1.z + r1 * C1.z, 0.f),
                      fmaxf(h7 + r0 * A1.w + r1 * C1.w, 0.f));
        *(u32x4*)(aw + g * 64 * 64) = pk;
      }
    }

    // --- single per-step drain+barrier: DMA/A-gen had the MFMA phase to fly ---
    asm volatile("s_waitcnt vmcnt(0) lgkmcnt(0)" ::: "memory");
    __builtin_amdgcn_s_barrier();
    __builtin_amdgcn_sched_barrier(0);
    cur ^= 1;
  }

  // --- final K-step (no prefetch) ---
  {
    const ushort_t* ab = cur ? &aLds[1][0] : &aLds[0][0];
    const ushort_t* bb = cur ? &bLds[1][0] : &bLds[0][0];
#pragma unroll
    for (int ki = 0; ki < 2; ++ki) {
      const int ao = ki ? aR1 : aR0;
      const int bo = ki ? bR1 : bR0;
      bf16x8 af[4];
#pragma unroll
      for (int mt = 0; mt < 4; ++mt)
        af[mt] = *(const bf16x8*)(ab + ao + mt * 1024);
#pragma unroll
      for (int nh = 0; nh < 2; ++nh) {
        bf16x8 bfr[4];
#pragma unroll
        for (int j = 0; j < 4; ++j)
          bfr[j] = *(const bf16x8*)(bb + bo + (nh * 4 + j) * 1024);
#pragma unroll
        for (int mt = 0; mt < 4; ++mt)
#pragma unroll
          for (int j = 0; j < 4; ++j)
            acc[mt][nh * 4 + j] = __builtin_amdgcn_mfma_f32_16x16x32_bf16(
                af[mt], bfr[j], acc[mt][nh * 4 + j], 0, 0, 0);
      }
    }
  }

  // ---- epilogue: max over b (32 rows per a-group), +b2, relu, store ----
  // acc[mt][nt] = C[wm*64 + mt*16 + q*4 + j][wn*128 + nt*16 + rl];
  // a_local = 2*wm + (mt>>1); b = (mt&1)*16 + q*4 + j.
#pragma unroll
  for (int g = 0; g < 2; ++g) {
    int orow = s * NPED + a0 + 2 * wm + g;
#pragma unroll
    for (int nt = 0; nt < 8; ++nt) {
      f32x4 x0 = acc[2 * g][nt], x1 = acc[2 * g + 1][nt];
      float v = fmaxf(fmaxf(fmaxf(x0.x, x0.y), fmaxf(x0.z, x0.w)),
                      fmaxf(fmaxf(x1.x, x1.y), fmaxf(x1.z, x1.w)));
      v = fmaxf(v, __shfl_xor(v, 16, 64));
      v = fmaxf(v, __shfl_xor(v, 32, 64));
      if (lane < 16) {
        int col = nb * BN + wn * 128 + nt * 16 + lane;
        float o = fmaxf(v + b2f[col], 0.f);
        if (isbf)
          ((ushort_t*)outv)[(size_t)orow * BOTN + col] = f2bf(o);
        else
          ((float*)outv)[(size_t)orow * BOTN + col] = o;
      }
    }
  }
}

extern "C" void kernel_launch(void* const* d_in, const int* in_sizes, int n_in,
                              void* d_out, int out_size, void* d_ws, size_t ws_size,
                              hipStream_t stream) {
  (void)in_sizes; (void)n_in; (void)out_size; (void)ws_size;
  const void* h_states = d_in[0];
  const void* end_pos = d_in[1];
  // d_in[2] rel_pos: unused by reference; d_in[3] seq_start_end: fixed equal scenes
  const void* W_sp = d_in[4];
  const void* b_sp = d_in[5];
  const void* W1 = d_in[6];
  const void* b1 = d_in[7];
  const void* W2 = d_in[8];
  const void* b2 = d_in[9];

  char* ws = (char*)d_ws;
  ushort_t* hcb = (ushort_t*)ws;                         // 8 MB  (512x8192 bf16)
  ushort_t* W2T = (ushort_t*)(ws + (8u << 20));          // 16 MB (1024x8192 bf16)
  float* M0f = (float*)(ws + (24u << 20));               // 32 KB
  float* M1f = (float*)(ws + (24u << 20) + 32768);       // 32 KB
  float* epf = (float*)(ws + (24u << 20) + 98304);       // 4 KB
  float* b2f = (float*)(ws + (24u << 20) + 102400);      // 4 KB
  int* flag = (int*)(ws + (24u << 20) + 106496);         // 4 B

  k_pre<<<dim3(2337), dim3(256), 0, stream>>>(
      h_states, end_pos, W_sp, b_sp, W1, b1, W2, b2,
      flag, epf, b2f, M0f, M1f, hcb, W2T);
  k_gemm<<<dim3(256), dim3(512), 0, stream>>>(hcb, M0f, M1f, W2T, epf, b2f, flag, d_out);
}